// Round 3
// baseline (258.299 us; speedup 1.0000x reference)
//
#include <hip/hip_runtime.h>
#include <cstdint>

typedef unsigned short u16;
typedef __attribute__((ext_vector_type(8))) short short8;
typedef __attribute__((ext_vector_type(16))) float f32x16;

// RNE float -> bf16 (bit pattern)
__device__ __forceinline__ u16 f2bf(float f) {
  uint32_t u = __float_as_uint(f);
  u += 0x7FFFu + ((u >> 16) & 1u);
  return (u16)(u >> 16);
}

// async global->LDS, 16B per lane. LDS dest must be wave-uniform base + lane*16.
__device__ __forceinline__ void async_ld16(u16* lds, const u16* g) {
  __builtin_amdgcn_global_load_lds((const __attribute__((address_space(1))) uint32_t*)g,
                                   (__attribute__((address_space(3))) uint32_t*)lds,
                                   16, 0, 0);
}

// phase fences (rule #18: sched_barrier(0) after inline-asm waitcnt)
__device__ __forceinline__ void lgkm0_fence() {
  asm volatile("s_waitcnt lgkmcnt(0)" ::: "memory");
  __builtin_amdgcn_sched_barrier(0);
}
__device__ __forceinline__ void vmw6_fence() {
  asm volatile("s_waitcnt vmcnt(6)" ::: "memory");
  __builtin_amdgcn_sched_barrier(0);
}
__device__ __forceinline__ void vmw0_fence() {
  asm volatile("s_waitcnt vmcnt(0)" ::: "memory");
  __builtin_amdgcn_sched_barrier(0);
}

#define MFMA32 __builtin_amdgcn_mfma_f32_32x32x16_bf16

// ---------------------------------------------------------------------------
// g8: 8-wave 4-phase/K-tile GEMM core (T2+T3+T4+T5), BK=64, K=1024 (16 tiles).
// Two geometries sharing one phase skeleton (acc[4][2], 24 ds_read + 32 MFMA
// per wave per K-tile, 8 global_load_lds per thread per K-tile, vmcnt(6)):
//   ROLE 0 (QK-fused, grid 256 = 1/CU): tile 256m x (128 Q | 128 K)n.
//     A = X rows (staged ONCE for both mats); B-LDS rows [0,128)=Wq, [128,256)=Wk.
//     j in acc[i][j] = mat. Exact 1 block/CU fixes r1's 1.5/CU imbalance.
//   ROLE 1 (grid 272): b<144: causal scores OPERAND-SWAPPED (A=K rows, B=Q rows
//     -> C[k][q]); per-lane col is one q => row-sum = 16-reg local sum + one
//     shfl_xor(32); P stored row-major via ushort4 runs of 4 contiguous k.
//     lpart in 128-wide k-chunks [zb][16][2048].
//     b>=144: V^T (A=Wtv rows d, B=X rows t, C=Vt ldc 8192). Vt last so the
//     16-block second round is the cheap-epilogue kind.
// ---------------------------------------------------------------------------
template <int ROLE>
__global__ __launch_bounds__(512, 2) void g8(
    const u16* __restrict__ Xbf, const u16* __restrict__ Wt,
    u16* __restrict__ QK, u16* __restrict__ VtAll,
    u16* __restrict__ P, float* __restrict__ lpart)
{
  const int b = blockIdx.x;
  const int tid = threadIdx.x;
  const int lane = tid & 63;
  const int wave = tid >> 6;
  const int wr2 = wave >> 2;   // 0..1: 128-row half of the 256-row tile
  const int wc2 = wave & 3;    // 0..3: n-slice
  const int m32 = lane & 31;
  const int hh = lane >> 5;

  __shared__ __align__(16) u16 ls[2][2][16384];  // [buf][A=0/B=1][256*64]

  // ---- per-role operand decode ----
  const u16 *Abase, *Bh0, *Bh1;
  int m0, n0, zb = 0;
  bool scoresRole = false;

  if constexpr (ROLE == 0) {
    m0 = (b >> 3) * 256;                 // 32 X-row tiles
    n0 = (b & 7) * 128;                  // 8 col tiles of 128
    Abase = Xbf;
    Bh0 = Wt;                            // Wq^T rows
    Bh1 = Wt + 1024L * 1024;             // Wk^T rows
  } else {
    if (b < 144) {
      scoresRole = true;
      zb = b / 36;
      const int w = b - zb * 36;
      int mt = 0;
      while ((mt + 1) * (mt + 2) / 2 <= w) ++mt;   // triangle, nt <= mt
      const int nt = w - mt * (mt + 1) / 2;
      // operand swap: A = K rows (k-tile nt), B = Q rows (q-tile mt)
      m0 = nt * 256;                     // k-base (m-dim)
      n0 = mt * 256;                     // q-base (n-dim)
      Abase = QK + 8192L * 1024 + (long)zb * 2048 * 1024;  // K-matrix
      const u16* Bq = QK + (long)zb * 2048 * 1024;          // Q-matrix
      Bh0 = Bq; Bh1 = Bq;                // halves resolved below via +128 rows
    } else {
      const int v = b - 144;
      m0 = (v >> 5) * 256;               // 4 d-tiles
      n0 = (v & 31) * 256;               // 32 t-tiles
      Abase = Wt + 2L * 1024 * 1024;     // Wtv rows d
      Bh0 = Xbf; Bh1 = Xbf;
    }
  }

  // ---- staging source pointers (pre-swizzled granule: src g = pos ^ (row&7)) ----
  const int sr = tid >> 3, sg = tid & 7;
  const long swz = (long)((sg ^ (sr & 7)) * 8);
  const u16* pAst = Abase + (long)(m0 + sr) * 1024 + swz;
  const u16* pB[2];
  if constexpr (ROLE == 0) {
    pB[0] = Bh0 + (long)(n0 + sr) * 1024 + swz;
    pB[1] = Bh1 + (long)(n0 + sr) * 1024 + swz;
  } else {
    pB[0] = Bh0 + (long)(n0 + sr) * 1024 + swz;
    pB[1] = Bh0 + (long)(n0 + 128 + sr) * 1024 + swz;
  }

#define STG_A(bf, h, t_) do { \
    u16* _d = &ls[bf][0][(h) * 8192] + tid * 8; \
    const u16* _s = pAst + (long)(h) * 131072 + (long)(t_) * 64; \
    async_ld16(_d, _s); async_ld16(_d + 4096, _s + 65536); } while (0)
#define STG_B(bf, h, t_) do { \
    u16* _d = &ls[bf][1][(h) * 8192] + tid * 8; \
    const u16* _s = pB[h] + (long)(t_) * 64; \
    async_ld16(_d, _s); async_ld16(_d + 4096, _s + 65536); } while (0)

  // ---- loop-invariant ds_read offsets (u16 units) ----
  int offAk[4], offBk[2][4];
#pragma unroll
  for (int ks = 0; ks < 4; ++ks) {
    const int kq = ((ks << 1) | hh) ^ (m32 & 7);
    offAk[ks] = (wr2 * 128 + m32) * 64 + kq * 8;
#pragma unroll
    for (int j = 0; j < 2; ++j) {
      const int rowB = (ROLE == 0) ? (j * 128 + wc2 * 32 + m32)
                                   : (wc2 * 64 + j * 32 + m32);
      offBk[j][ks] = rowB * 64 + kq * 8;
    }
  }

  f32x16 acc[4][2];
#pragma unroll
  for (int i = 0; i < 4; ++i)
#pragma unroll
    for (int j = 0; j < 2; ++j)
#pragma unroll
      for (int r = 0; r < 16; ++r) acc[i][j][r] = 0.f;

  // ---- prologue: tile0 complete (8 loads) + tile1 {B0,B1,A0} (6 loads) ----
  STG_A(0, 0, 0); STG_A(0, 1, 0); STG_B(0, 0, 0); STG_B(0, 1, 0);
  STG_B(1, 0, 1); STG_B(1, 1, 1); STG_A(1, 0, 1);
  vmw6_fence();
  __builtin_amdgcn_s_barrier();

  short8 A0[4], A1[4], A2[4], A3[4], B0r[4], B1r[4];

#pragma unroll 1
  for (int t = 0; t < 16; ++t) {
    const u16* la = ls[t & 1][0];
    const u16* lb = ls[t & 1][1];

    // ---- phase 0: read A0,A1,B(j=0) | stage (t+1).A1 | mfma (m0,m1)x j0
#pragma unroll
    for (int ks = 0; ks < 4; ++ks) {
      A0[ks]  = *(const short8*)&la[offAk[ks]];
      A1[ks]  = *(const short8*)&la[offAk[ks] + 2048];
      B0r[ks] = *(const short8*)&lb[offBk[0][ks]];
    }
    if (t < 15) STG_A((t + 1) & 1, 1, t + 1);
    __builtin_amdgcn_s_barrier();
    lgkm0_fence();
    __builtin_amdgcn_s_setprio(1);
#pragma unroll
    for (int ks = 0; ks < 4; ++ks) {
      acc[0][0] = MFMA32(A0[ks], B0r[ks], acc[0][0], 0, 0, 0);
      acc[1][0] = MFMA32(A1[ks], B0r[ks], acc[1][0], 0, 0, 0);
    }
    __builtin_amdgcn_s_setprio(0);
    __builtin_amdgcn_s_barrier();

    // ---- phase 1: read B(j=1) | mfma (m0,m1)x j1
#pragma unroll
    for (int ks = 0; ks < 4; ++ks)
      B1r[ks] = *(const short8*)&lb[offBk[1][ks]];
    __builtin_amdgcn_s_barrier();
    lgkm0_fence();
    __builtin_amdgcn_s_setprio(1);
#pragma unroll
    for (int ks = 0; ks < 4; ++ks) {
      acc[0][1] = MFMA32(A0[ks], B1r[ks], acc[0][1], 0, 0, 0);
      acc[1][1] = MFMA32(A1[ks], B1r[ks], acc[1][1], 0, 0, 0);
    }
    __builtin_amdgcn_s_setprio(0);
    __builtin_amdgcn_s_barrier();

    // ---- phase 2: read A2,A3 | stage (t+2).B0 | mfma (m2,m3)x j0
#pragma unroll
    for (int ks = 0; ks < 4; ++ks) {
      A2[ks] = *(const short8*)&la[offAk[ks] + 4096];
      A3[ks] = *(const short8*)&la[offAk[ks] + 6144];
    }
    if (t < 14) STG_B(t & 1, 0, t + 2);
    __builtin_amdgcn_s_barrier();
    lgkm0_fence();
    __builtin_amdgcn_s_setprio(1);
#pragma unroll
    for (int ks = 0; ks < 4; ++ks) {
      acc[2][0] = MFMA32(A2[ks], B0r[ks], acc[2][0], 0, 0, 0);
      acc[3][0] = MFMA32(A3[ks], B0r[ks], acc[3][0], 0, 0, 0);
    }
    __builtin_amdgcn_s_setprio(0);
    __builtin_amdgcn_s_barrier();

    // ---- phase 3: stage (t+2).{B1,A0} | mfma (m2,m3)x j1 | vmcnt(6)
    if (t < 14) { STG_B(t & 1, 1, t + 2); STG_A(t & 1, 0, t + 2); }
    __builtin_amdgcn_s_barrier();
    __builtin_amdgcn_s_setprio(1);
#pragma unroll
    for (int ks = 0; ks < 4; ++ks) {
      acc[2][1] = MFMA32(A2[ks], B1r[ks], acc[2][1], 0, 0, 0);
      acc[3][1] = MFMA32(A3[ks], B1r[ks], acc[3][1], 0, 0, 0);
    }
    __builtin_amdgcn_s_setprio(0);
    if (t < 14) vmw6_fence(); else vmw0_fence();
    __builtin_amdgcn_s_barrier();
  }
#undef STG_A
#undef STG_B

  // C/D layout 32x32 (m74/m101): col = lane&31, row = (reg&3)+8*(reg>>2)+4*(lane>>5)
  const int ec = lane & 31;
  const int rb = hh * 4;

  if constexpr (ROLE == 0) {
#pragma unroll
    for (int j = 0; j < 2; ++j) {
      u16* Cj = QK + (long)j * 8192 * 1024;
      const int col = n0 + wc2 * 32 + ec;
#pragma unroll
      for (int i = 0; i < 4; ++i) {
        const int rbase = m0 + wr2 * 128 + i * 32 + rb;
#pragma unroll
        for (int r = 0; r < 16; ++r) {
          const int row = rbase + (r & 3) + 8 * (r >> 2);
          Cj[(long)row * 1024 + col] = f2bf(acc[i][j][r]);
        }
      }
    }
  } else if (scoresRole) {
    u16* Pp = P + (long)zb * 2048 * 2048;
    float* lpz = lpart + (long)zb * 16 * 2048;
    const int chunk = (m0 >> 7) + wr2;     // 128-wide k-chunk index
#pragma unroll
    for (int j = 0; j < 2; ++j) {
      const int q = n0 + wc2 * 64 + j * 32 + ec;
      float s = 0.f;
#pragma unroll
      for (int i = 0; i < 4; ++i) {
        const int kb = m0 + wr2 * 128 + i * 32 + rb;
#pragma unroll
        for (int u = 0; u < 4; ++u) {
          const int k0r = kb + u * 8;
          float pv[4];
#pragma unroll
          for (int v = 0; v < 4; ++v) {
            float e = __expf(acc[i][j][u * 4 + v] * 0.03125f);
            if (k0r + v > q) e = 0.f;
            pv[v] = e;
            s += e;
          }
          ushort4 o;
          o.x = f2bf(pv[0]); o.y = f2bf(pv[1]);
          o.z = f2bf(pv[2]); o.w = f2bf(pv[3]);
          *(ushort4*)&Pp[(long)q * 2048 + k0r] = o;
        }
      }
      s += __shfl_xor(s, 32, 64);
      if (hh == 0) lpz[(long)chunk * 2048 + q] = s;
    }
  } else {
    // Vt[d][t_global]: ldc = 8192
#pragma unroll
    for (int i = 0; i < 4; ++i) {
      const int rbase = m0 + wr2 * 128 + i * 32 + rb;
#pragma unroll
      for (int j = 0; j < 2; ++j) {
        const int col = n0 + wc2 * 64 + j * 32 + ec;
#pragma unroll
        for (int r = 0; r < 16; ++r) {
          const int row = rbase + (r & 3) + 8 * (r >> 2);
          VtAll[(long)row * 8192 + col] = f2bf(acc[i][j][r]);
        }
      }
    }
  }
}

// ---------------------------------------------------------------------------
// PV: tile 128(q) x 64(d), BK=32 double-buffered, grid (256,4) = 4 blocks/CU
// (r1's 128x128/512-block version was TLP-starved at 2 blocks/CU: 0.97 vs
// 0.52 us/K-unit). 4 waves 2x2, per-wave 64x32 (acc 2 x f32x16). K clipped at
// the causal diagonal; epilogue builds 1/l from 128-wide lpart chunks.
// ---------------------------------------------------------------------------
__global__ __launch_bounds__(256) void pv(
    const u16* __restrict__ VtAll, const u16* __restrict__ P,
    const float* __restrict__ lpart, float* __restrict__ out)
{
  const int b = blockIdx.x;
  const int tid = threadIdx.x;
  const int lane = tid & 63;
  const int wave = tid >> 6;
  const int wr = (wave >> 1) * 64;   // q-rows half
  const int wc = (wave & 1) * 32;    // d-cols half

  __shared__ __align__(16) u16 lsa[2][4096];  // P tile 128x32
  __shared__ __align__(16) u16 lsb[2][2048];  // Vt tile 64x32
  __shared__ float l_s[128];

  const int zb = blockIdx.y;
  const int mb = 15 - (b >> 4);      // big-K blocks first
  const int nb = b & 15;
  const int m0 = mb * 128;
  const int n0 = nb * 64;
  const int kmax = (mb + 1) * 128;

  const u16* A = P + (long)zb * 2048 * 2048;          // lda 2048
  const u16* B = VtAll + (long)zb * 2048;             // ldb 8192, rows d

  // staging slots (A: 512 granules -> c0,c1; B: 256 granules -> c0)
  const int c0 = tid, c1 = tid + 256;
  const int r0 = c0 >> 2, q0 = ((c0 & 3) ^ ((c0 >> 3) & 3)) * 8;
  const int r1 = c1 >> 2, q1 = ((c1 & 3) ^ ((c1 >> 3) & 3)) * 8;

  const int m32 = lane & 31;
  const int hh = lane >> 5;
  const int rsw = (m32 >> 1) & 3;
  int offA[2][2], offB[2];
#pragma unroll
  for (int ks = 0; ks < 2; ++ks) {
    const int kq = ((ks << 1) | hh) ^ rsw;
#pragma unroll
    for (int i = 0; i < 2; ++i)
      offA[i][ks] = (wr + i * 32 + m32) * 32 + kq * 8;
    offB[ks] = (wc + m32) * 32 + kq * 8;
  }

  const u16* pA0 = A + (long)(m0 + r0) * 2048 + q0;
  const u16* pA1 = A + (long)(m0 + r1) * 2048 + q1;
  const u16* pB0 = B + (long)(n0 + r0) * 8192 + q0;

  f32x16 acc[2];
#pragma unroll
  for (int i = 0; i < 2; ++i)
#pragma unroll
    for (int r = 0; r < 16; ++r) acc[i][r] = 0.f;

  async_ld16(&lsa[0][c0 * 8], pA0);
  async_ld16(&lsa[0][c1 * 8], pA1);
  async_ld16(&lsb[0][c0 * 8], pB0);
  pA0 += 32; pA1 += 32; pB0 += 32;

  int p = 0;
  for (int k0 = 0; k0 < kmax; k0 += 32) {
    __syncthreads();
    if (k0 + 32 < kmax) {
      async_ld16(&lsa[p ^ 1][c0 * 8], pA0);
      async_ld16(&lsa[p ^ 1][c1 * 8], pA1);
      async_ld16(&lsb[p ^ 1][c0 * 8], pB0);
      pA0 += 32; pA1 += 32; pB0 += 32;
    }
    const u16* la = lsa[p];
    const u16* lb = lsb[p];
#pragma unroll
    for (int ks = 0; ks < 2; ++ks) {
      const short8 a0 = *(const short8*)&la[offA[0][ks]];
      const short8 a1 = *(const short8*)&la[offA[1][ks]];
      const short8 bb = *(const short8*)&lb[offB[ks]];
      acc[0] = MFMA32(a0, bb, acc[0], 0, 0, 0);
      acc[1] = MFMA32(a1, bb, acc[1], 0, 0, 0);
    }
    p ^= 1;
  }

  // epilogue: 1/l per row from 128-wide lpart chunks
  __syncthreads();
  if (tid < 128) {
    const float* lp = lpart + (long)zb * 16 * 2048 + m0 + tid;
    float s = 0.f;
    const int nch = (mb | 1) + 1;
    for (int c = 0; c < nch; ++c) s += lp[(long)c * 2048];
    l_s[tid] = 1.f / s;
  }
  __syncthreads();

  const int ec = lane & 31;
  const int rb = hh * 4;
  float* Cf = out + (long)zb * 2048 * 1024;
#pragma unroll
  for (int i = 0; i < 2; ++i) {
    const int rbl = wr + i * 32 + rb;
    const int col = n0 + wc + ec;
#pragma unroll
    for (int r = 0; r < 16; ++r) {
      const int rl = rbl + (r & 3) + 8 * (r >> 2);
      Cf[(long)(m0 + rl) * 1024 + col] = acc[i][r] * l_s[rl];
    }
  }
}

// ---------------------------------------------------------------------------
// Fused casts: blocks [0,8192): X fp32->bf16 (1024 elems each);
// blocks [8192,11264): W_{q,k,v}[k][n] fp32 -> Wt[n][k] bf16 (32x32 tiles).
// ---------------------------------------------------------------------------
__global__ __launch_bounds__(256) void cast_fused(
    const float* __restrict__ x, const float* __restrict__ w0,
    const float* __restrict__ w1, const float* __restrict__ w2,
    u16* __restrict__ Xbf, u16* __restrict__ Wt)
{
  const int b = blockIdx.x;
  if (b < 8192) {
    const long i = ((long)b * 256 + threadIdx.x) * 4;
    const float4 v = *(const float4*)(x + i);
    ushort4 o;
    o.x = f2bf(v.x); o.y = f2bf(v.y); o.z = f2bf(v.z); o.w = f2bf(v.w);
    *(ushort4*)(Xbf + i) = o;
  } else {
    const int bb = b - 8192;               // [0,3072)
    const int z = bb >> 10, rem = bb & 1023;
    const float* W = (z == 0) ? w0 : (z == 1) ? w1 : w2;
    u16* o = Wt + (long)z * 1024 * 1024;
    __shared__ float t[32][33];
    const int n0 = (rem & 31) * 32, k0 = (rem >> 5) * 32;
    const int tx = threadIdx.x & 31, ty = threadIdx.x >> 5;
    for (int r = ty; r < 32; r += 8) t[r][tx] = W[(long)(k0 + r) * 1024 + n0 + tx];
    __syncthreads();
    for (int r = ty; r < 32; r += 8) o[(long)(n0 + r) * 1024 + k0 + tx] = f2bf(t[tx][r]);
  }
}

// ---------------------------------------------------------------------------
extern "C" void kernel_launch(void* const* d_in, const int* in_sizes, int n_in,
                              void* d_out, int out_size, void* d_ws, size_t ws_size,
                              hipStream_t stream) {
  const float* X  = (const float*)d_in[0];
  const float* Wq = (const float*)d_in[1];
  const float* Wk = (const float*)d_in[2];
  const float* Wv = (const float*)d_in[3];
  float* out = (float*)d_out;

  // workspace (~103 MiB)
  u16* Xbf   = (u16*)d_ws;                   // 8192*1024            16 MB
  u16* Wt    = Xbf + 8192L * 1024;           // 3*1024*1024           6 MB
  u16* QK    = Wt + 3L * 1024 * 1024;        // 2*8192*1024          32 MB
  u16* VtAll = QK + 2L * 8192 * 1024;        // 1024*8192            16 MB
  u16* P     = VtAll + 1024L * 8192;         // 4*2048*2048          32 MB
  float* lpart = (float*)(P + 4L * 2048 * 2048);  // 4*16*2048 fp32  0.5 MB

  cast_fused<<<8192 + 3072, 256, 0, stream>>>(X, Wq, Wk, Wv, Xbf, Wt);

  // Q+K fused projection: 256 blocks = exactly 1/CU
  g8<0><<<256, 512, 0, stream>>>(Xbf, Wt, QK, VtAll, P, lpart);

  // causal scores (144, heavy epi first) + V^T (128, light epi last) = 272
  g8<1><<<272, 512, 0, stream>>>(Xbf, Wt, QK, VtAll, P, lpart);

  // PV: 1024 blocks (4/CU), big-K-first, epilogue normalizes via lpart
  pv<<<dim3(256, 4), 256, 0, stream>>>(VtAll, P, lpart, out);
}

// Round 4
// 228.044 us; speedup vs baseline: 1.1327x; 1.1327x over previous
//
#include <hip/hip_runtime.h>
#include <cstdint>

typedef unsigned short u16;
typedef __attribute__((ext_vector_type(8))) short short8;
typedef __attribute__((ext_vector_type(16))) float f32x16;

// RNE float -> bf16 (bit pattern)
__device__ __forceinline__ u16 f2bf(float f) {
  uint32_t u = __float_as_uint(f);
  u += 0x7FFFu + ((u >> 16) & 1u);
  return (u16)(u >> 16);
}

// async global->LDS, 16B per lane. LDS dest must be wave-uniform base + lane*16.
__device__ __forceinline__ void async_ld16(u16* lds, const u16* g) {
  __builtin_amdgcn_global_load_lds((const __attribute__((address_space(1))) uint32_t*)g,
                                   (__attribute__((address_space(3))) uint32_t*)lds,
                                   16, 0, 0);
}

// phase fences (rule #18: sched_barrier(0) after inline-asm waitcnt)
__device__ __forceinline__ void lgkm0_fence() {
  asm volatile("s_waitcnt lgkmcnt(0)" ::: "memory");
  __builtin_amdgcn_sched_barrier(0);
}
#define VM_FENCE(N) do { asm volatile("s_waitcnt vmcnt(" #N ")" ::: "memory"); \
                         __builtin_amdgcn_sched_barrier(0); } while (0)

#define MFMA32 __builtin_amdgcn_mfma_f32_32x32x16_bf16

// ---------------------------------------------------------------------------
// g8: 8-wave GEMM cores sharing LDS/staging swizzle (granule g^(row&7), linear
// LDS dest, pre-swizzled global src).
// ROLE 0, b<256  : dense 256x(128Q|128K) QK-fused projection, 4-phase BK64
//                  skeleton (unchanged from r3, proven).
// ROLE 0, b>=256 : Vt HALF blocks (BM=128 d, BN=256 t), 2-phase BK64,
//                  counted vmcnt ledger {ph0-end: vm(4), ph1-end: vm(2)}.
//                  These backfill the CUs as a ~half-length second round.
// ROLE 1 (144)   : causal scores, operand-swapped (A=K rows -> C[k][q]),
//                  dense 4-phase skeleton; P bf16 + 128-wide lpart chunks.
// ---------------------------------------------------------------------------
template <int ROLE>
__global__ __launch_bounds__(512, 2) void g8(
    const u16* __restrict__ Xbf, const u16* __restrict__ Wt,
    u16* __restrict__ QK, u16* __restrict__ VtAll,
    u16* __restrict__ P, float* __restrict__ lpart)
{
  const int b = blockIdx.x;
  const int tid = threadIdx.x;
  const int lane = tid & 63;
  const int wave = tid >> 6;
  const int wr2 = wave >> 2;   // 0..1
  const int wc2 = wave & 3;    // 0..3
  const int m32 = lane & 31;
  const int hh = lane >> 5;

  __shared__ __align__(16) u16 ls[2][2][16384];  // [buf][A=0/B=1]

  // ---- per-role operand decode ----
  const u16 *Abase, *Brow0, *Brow1;   // Brow1 = base for B rows [128,256)
  int m0, n0, zb = 0;
  bool vthalf = false;

  if constexpr (ROLE == 0) {
    if (b < 256) {                       // dense QK-fused
      m0 = (b >> 3) * 256;
      n0 = (b & 7) * 128;
      Abase = Xbf;
      Brow0 = Wt + (long)(n0)*1024;                    // Wq rows n0..
      Brow1 = Wt + 1024L * 1024 + (long)(n0)*1024;     // Wk rows n0..
    } else {                             // Vt half block
      vthalf = true;
      const int v = b - 256;
      m0 = (v >> 5) * 128;               // 8 d-tiles of 128
      n0 = (v & 31) * 256;               // 32 t-tiles of 256
      Abase = Wt + 2L * 1024 * 1024;     // Wtv rows d
      Brow0 = Xbf + (long)(n0)*1024;
      Brow1 = Xbf + (long)(n0 + 128) * 1024;
    }
  } else {                               // causal scores
    zb = b / 36;
    const int w = b - zb * 36;
    int mt = 0;
    while ((mt + 1) * (mt + 2) / 2 <= w) ++mt;   // triangle, nt <= mt
    const int nt = w - mt * (mt + 1) / 2;
    m0 = nt * 256;                       // k-base (M dim, swapped)
    n0 = mt * 256;                       // q-base (N dim)
    Abase = QK + 8192L * 1024 + (long)zb * 2048 * 1024;   // K rows
    const u16* Bq = QK + (long)zb * 2048 * 1024;          // Q rows
    Brow0 = Bq + (long)(n0)*1024;
    Brow1 = Bq + (long)(n0 + 128) * 1024;
  }

  // ---- staging source pointers (pre-swizzled granule) ----
  const int sr = tid >> 3, sg = tid & 7;
  const long swz = (long)((sg ^ (sr & 7)) * 8);
  const u16* pAst = Abase + (long)(m0 + sr) * 1024 + swz;
  const u16* pB[2] = { Brow0 + (long)sr * 1024 + swz,
                       Brow1 + (long)sr * 1024 + swz };

#define STG_A(bf, h, t_) do { \
    u16* _d = &ls[bf][0][(h) * 8192] + tid * 8; \
    const u16* _s = pAst + (long)(h) * 131072 + (long)(t_) * 64; \
    async_ld16(_d, _s); async_ld16(_d + 4096, _s + 65536); } while (0)
#define STG_B(bf, h, t_) do { \
    u16* _d = &ls[bf][1][(h) * 8192] + tid * 8; \
    const u16* _s = pB[h] + (long)(t_) * 64; \
    async_ld16(_d, _s); async_ld16(_d + 4096, _s + 65536); } while (0)

  const int ec = lane & 31;
  const int rb = hh * 4;

  // =========================================================================
  // Vt HALF-BLOCK path (ROLE 0, b>=256): BM=128, BN=256, 2 phases per K-tile
  // =========================================================================
  if constexpr (ROLE == 0) {
    if (vthalf) {
      int offAv[4], offBv[2][4];
#pragma unroll
      for (int ks = 0; ks < 4; ++ks) {
        const int kq = ((ks << 1) | hh) ^ (m32 & 7);
        offAv[ks] = (wr2 * 64 + m32) * 64 + kq * 8;
#pragma unroll
        for (int j = 0; j < 2; ++j)
          offBv[j][ks] = (wc2 * 64 + j * 32 + m32) * 64 + kq * 8;
      }

      f32x16 acc[2][2];
#pragma unroll
      for (int i = 0; i < 2; ++i)
#pragma unroll
        for (int j = 0; j < 2; ++j)
#pragma unroll
          for (int r = 0; r < 16; ++r) acc[i][j][r] = 0.f;

      // prologue: tile0 complete (A=2, B=4 loads), drain
      STG_A(0, 0, 0); STG_B(0, 0, 0); STG_B(0, 1, 0);
      VM_FENCE(0);
      __builtin_amdgcn_s_barrier();

      short8 A0[4], A1[4], B0r[4], B1r[4];

#pragma unroll 1
      for (int t = 0; t < 16; ++t) {
        const u16* la = ls[t & 1][0];
        const u16* lb = ls[t & 1][1];
        const int nb = (t & 1) ^ 1;

        // ph0: read A0,A1,B0 | stage (t+1).{A, B-half0} | mfma j=0
#pragma unroll
        for (int ks = 0; ks < 4; ++ks) {
          A0[ks]  = *(const short8*)&la[offAv[ks]];
          A1[ks]  = *(const short8*)&la[offAv[ks] + 2048];
          B0r[ks] = *(const short8*)&lb[offBv[0][ks]];
        }
        if (t < 15) { STG_A(nb, 0, t + 1); STG_B(nb, 0, t + 1); }
        __builtin_amdgcn_s_barrier();
        lgkm0_fence();
        __builtin_amdgcn_s_setprio(1);
#pragma unroll
        for (int ks = 0; ks < 4; ++ks) {
          acc[0][0] = MFMA32(A0[ks], B0r[ks], acc[0][0], 0, 0, 0);
          acc[1][0] = MFMA32(A1[ks], B0r[ks], acc[1][0], 0, 0, 0);
        }
        __builtin_amdgcn_s_setprio(0);
        if (t < 15) VM_FENCE(4); else VM_FENCE(0);   // retire prev B-half1
        __builtin_amdgcn_s_barrier();

        // ph1: read B1 | stage (t+1).B-half1 | mfma j=1
#pragma unroll
        for (int ks = 0; ks < 4; ++ks)
          B1r[ks] = *(const short8*)&lb[offBv[1][ks]];
        if (t < 15) STG_B(nb, 1, t + 1);
        __builtin_amdgcn_s_barrier();
        lgkm0_fence();
        __builtin_amdgcn_s_setprio(1);
#pragma unroll
        for (int ks = 0; ks < 4; ++ks) {
          acc[0][1] = MFMA32(A0[ks], B1r[ks], acc[0][1], 0, 0, 0);
          acc[1][1] = MFMA32(A1[ks], B1r[ks], acc[1][1], 0, 0, 0);
        }
        __builtin_amdgcn_s_setprio(0);
        if (t < 15) VM_FENCE(2); else VM_FENCE(0);   // retire next A + B-half0
        __builtin_amdgcn_s_barrier();
      }

      // epilogue: Vt[d][t_global], ldc = 8192
#pragma unroll
      for (int i = 0; i < 2; ++i) {
        const int rbase = m0 + wr2 * 64 + i * 32 + rb;
#pragma unroll
        for (int j = 0; j < 2; ++j) {
          const int col = n0 + wc2 * 64 + j * 32 + ec;
#pragma unroll
          for (int r = 0; r < 16; ++r) {
            const int row = rbase + (r & 3) + 8 * (r >> 2);
            VtAll[(long)row * 8192 + col] = f2bf(acc[i][j][r]);
          }
        }
      }
      return;
    }
  }

  // =========================================================================
  // Dense 4-phase skeleton (ROLE0 b<256 QK-fused; ROLE1 scores) — unchanged
  // =========================================================================
  int offAk[4], offBk[2][4];
#pragma unroll
  for (int ks = 0; ks < 4; ++ks) {
    const int kq = ((ks << 1) | hh) ^ (m32 & 7);
    offAk[ks] = (wr2 * 128 + m32) * 64 + kq * 8;
#pragma unroll
    for (int j = 0; j < 2; ++j) {
      const int rowB = (ROLE == 0) ? (j * 128 + wc2 * 32 + m32)
                                   : (wc2 * 64 + j * 32 + m32);
      offBk[j][ks] = rowB * 64 + kq * 8;
    }
  }

  f32x16 acc[4][2];
#pragma unroll
  for (int i = 0; i < 4; ++i)
#pragma unroll
    for (int j = 0; j < 2; ++j)
#pragma unroll
      for (int r = 0; r < 16; ++r) acc[i][j][r] = 0.f;

  // prologue: tile0 complete (8 loads) + tile1 {B0,B1,A0} (6 loads)
  STG_A(0, 0, 0); STG_A(0, 1, 0); STG_B(0, 0, 0); STG_B(0, 1, 0);
  STG_B(1, 0, 1); STG_B(1, 1, 1); STG_A(1, 0, 1);
  VM_FENCE(6);
  __builtin_amdgcn_s_barrier();

  short8 A0[4], A1[4], A2[4], A3[4], B0r[4], B1r[4];

#pragma unroll 1
  for (int t = 0; t < 16; ++t) {
    const u16* la = ls[t & 1][0];
    const u16* lb = ls[t & 1][1];

    // ph0: read A0,A1,B0 | stage (t+1).A1 | mfma (m0,m1)xj0
#pragma unroll
    for (int ks = 0; ks < 4; ++ks) {
      A0[ks]  = *(const short8*)&la[offAk[ks]];
      A1[ks]  = *(const short8*)&la[offAk[ks] + 2048];
      B0r[ks] = *(const short8*)&lb[offBk[0][ks]];
    }
    if (t < 15) STG_A((t + 1) & 1, 1, t + 1);
    __builtin_amdgcn_s_barrier();
    lgkm0_fence();
    __builtin_amdgcn_s_setprio(1);
#pragma unroll
    for (int ks = 0; ks < 4; ++ks) {
      acc[0][0] = MFMA32(A0[ks], B0r[ks], acc[0][0], 0, 0, 0);
      acc[1][0] = MFMA32(A1[ks], B0r[ks], acc[1][0], 0, 0, 0);
    }
    __builtin_amdgcn_s_setprio(0);
    __builtin_amdgcn_s_barrier();

    // ph1: read B1 | mfma (m0,m1)xj1
#pragma unroll
    for (int ks = 0; ks < 4; ++ks)
      B1r[ks] = *(const short8*)&lb[offBk[1][ks]];
    __builtin_amdgcn_s_barrier();
    lgkm0_fence();
    __builtin_amdgcn_s_setprio(1);
#pragma unroll
    for (int ks = 0; ks < 4; ++ks) {
      acc[0][1] = MFMA32(A0[ks], B1r[ks], acc[0][1], 0, 0, 0);
      acc[1][1] = MFMA32(A1[ks], B1r[ks], acc[1][1], 0, 0, 0);
    }
    __builtin_amdgcn_s_setprio(0);
    __builtin_amdgcn_s_barrier();

    // ph2: read A2,A3 | stage (t+2).B0 | mfma (m2,m3)xj0
#pragma unroll
    for (int ks = 0; ks < 4; ++ks) {
      A2[ks] = *(const short8*)&la[offAk[ks] + 4096];
      A3[ks] = *(const short8*)&la[offAk[ks] + 6144];
    }
    if (t < 14) STG_B(t & 1, 0, t + 2);
    __builtin_amdgcn_s_barrier();
    lgkm0_fence();
    __builtin_amdgcn_s_setprio(1);
#pragma unroll
    for (int ks = 0; ks < 4; ++ks) {
      acc[2][0] = MFMA32(A2[ks], B0r[ks], acc[2][0], 0, 0, 0);
      acc[3][0] = MFMA32(A3[ks], B0r[ks], acc[3][0], 0, 0, 0);
    }
    __builtin_amdgcn_s_setprio(0);
    __builtin_amdgcn_s_barrier();

    // ph3: stage (t+2).{B1,A0} | mfma (m2,m3)xj1 | counted vmcnt
    if (t < 14) { STG_B(t & 1, 1, t + 2); STG_A(t & 1, 0, t + 2); }
    __builtin_amdgcn_s_barrier();
    __builtin_amdgcn_s_setprio(1);
#pragma unroll
    for (int ks = 0; ks < 4; ++ks) {
      acc[2][1] = MFMA32(A2[ks], B1r[ks], acc[2][1], 0, 0, 0);
      acc[3][1] = MFMA32(A3[ks], B1r[ks], acc[3][1], 0, 0, 0);
    }
    __builtin_amdgcn_s_setprio(0);
    if (t < 14) VM_FENCE(6); else VM_FENCE(0);
    __builtin_amdgcn_s_barrier();
  }
#undef STG_A
#undef STG_B

  // C/D layout 32x32 (m74/m101): col = lane&31, row = (reg&3)+8*(reg>>2)+4*(lane>>5)
  if constexpr (ROLE == 0) {
#pragma unroll
    for (int j = 0; j < 2; ++j) {
      u16* Cj = QK + (long)j * 8192 * 1024;
      const int col = n0 + wc2 * 32 + ec;
#pragma unroll
      for (int i = 0; i < 4; ++i) {
        const int rbase = m0 + wr2 * 128 + i * 32 + rb;
#pragma unroll
        for (int r = 0; r < 16; ++r) {
          const int row = rbase + (r & 3) + 8 * (r >> 2);
          Cj[(long)row * 1024 + col] = f2bf(acc[i][j][r]);
        }
      }
    }
  } else {
    u16* Pp = P + (long)zb * 2048 * 2048;
    float* lpz = lpart + (long)zb * 16 * 2048;
    const int chunk = (m0 >> 7) + wr2;     // 128-wide k-chunk index
#pragma unroll
    for (int j = 0; j < 2; ++j) {
      const int q = n0 + wc2 * 64 + j * 32 + ec;
      float s = 0.f;
#pragma unroll
      for (int i = 0; i < 4; ++i) {
        const int kb = m0 + wr2 * 128 + i * 32 + rb;
#pragma unroll
        for (int u = 0; u < 4; ++u) {
          const int k0r = kb + u * 8;
          float pv4[4];
#pragma unroll
          for (int v = 0; v < 4; ++v) {
            float e = __expf(acc[i][j][u * 4 + v] * 0.03125f);
            if (k0r + v > q) e = 0.f;
            pv4[v] = e;
            s += e;
          }
          ushort4 o;
          o.x = f2bf(pv4[0]); o.y = f2bf(pv4[1]);
          o.z = f2bf(pv4[2]); o.w = f2bf(pv4[3]);
          *(ushort4*)&Pp[(long)q * 2048 + k0r] = o;
        }
      }
      s += __shfl_xor(s, 32, 64);
      if (hh == 0) lpz[(long)chunk * 2048 + q] = s;
    }
  }
}

// ---------------------------------------------------------------------------
// PV: 512 blocks x 4 waves, BM=128(q) x BN=128(d), BK=64, LDS 64 KiB ->
// 2 blocks/CU. Complementary pairing: blocks [0,256) carry qt=15-pp (big),
// [256,512) carry qt=pp (small) with identical (zb,dn,pp) decode, so each CU
// hosts one big + one small block (34 K-tiles combined, uniform). m97-style
// single-__syncthreads double-buffered loop: 8 waves/CU TLP hides the drain.
// Epilogue: 1/l per q-row from 128-wide lpart chunks (qt+1 chunks exactly).
// ---------------------------------------------------------------------------
__global__ __launch_bounds__(256) void pv(
    const u16* __restrict__ VtAll, const u16* __restrict__ P,
    const float* __restrict__ lpart, float* __restrict__ out)
{
  const int b = blockIdx.x;
  const int tid = threadIdx.x;
  const int lane = tid & 63;
  const int wave = tid >> 6;
  const int wm = wave >> 1;          // q half (64)
  const int wn = wave & 1;           // d half (64)
  const int m32 = lane & 31;
  const int hh = lane >> 5;

  __shared__ __align__(16) u16 lsa[2][8192];  // P tile 128x64
  __shared__ __align__(16) u16 lsb[2][8192];  // Vt tile 128x64
  __shared__ float l_s[128];

  const int id = b & 255;
  const int zb = id >> 6;
  const int r2 = id & 63;
  const int dn = r2 >> 3;
  const int pp = r2 & 7;
  const int qt = (b < 256) ? (15 - pp) : pp;
  const int m0 = qt * 128;           // q base
  const int n0 = dn * 128;           // d base
  const int nkt = (qt + 1) * 2;      // BK64 tiles up to causal diagonal

  const u16* Ab = P + (long)zb * 2048 * 2048;        // P rows q, lda 2048
  const u16* Bb = VtAll + (long)zb * 2048;           // Vt rows d, ldb 8192

  const int prow = tid >> 3;
  const long pswz = (long)(((tid & 7) ^ (prow & 7)) * 8);
  const u16* pA = Ab + (long)(m0 + prow) * 2048 + pswz;
  const u16* pB = Bb + (long)(n0 + prow) * 8192 + pswz;

#define PV_STG(bf, t_) do { \
    _Pragma("unroll") \
    for (int jj = 0; jj < 4; ++jj) { \
      async_ld16(&lsa[bf][(tid + jj * 256) * 8], pA + (long)jj * 32 * 2048 + (long)(t_) * 64); \
      async_ld16(&lsb[bf][(tid + jj * 256) * 8], pB + (long)jj * 32 * 8192 + (long)(t_) * 64); \
    } } while (0)

  int offA[2][4], offB[2][4];
#pragma unroll
  for (int ks = 0; ks < 4; ++ks) {
    const int kq = ((ks << 1) | hh) ^ (m32 & 7);
#pragma unroll
    for (int i = 0; i < 2; ++i) {
      offA[i][ks] = (wm * 64 + i * 32 + m32) * 64 + kq * 8;
      offB[i][ks] = (wn * 64 + i * 32 + m32) * 64 + kq * 8;
    }
  }

  f32x16 acc[2][2];
#pragma unroll
  for (int i = 0; i < 2; ++i)
#pragma unroll
    for (int j = 0; j < 2; ++j)
#pragma unroll
      for (int r = 0; r < 16; ++r) acc[i][j][r] = 0.f;

  PV_STG(0, 0);

#pragma unroll 1
  for (int t = 0; t < nkt; ++t) {
    __syncthreads();                       // drains vmcnt: buf[t&1] ready
    if (t + 1 < nkt) PV_STG((t & 1) ^ 1, t + 1);
    const u16* la = lsa[t & 1];
    const u16* lb = lsb[t & 1];
#pragma unroll
    for (int ks = 0; ks < 4; ++ks) {
      const short8 a0 = *(const short8*)&la[offA[0][ks]];
      const short8 a1 = *(const short8*)&la[offA[1][ks]];
      const short8 b0 = *(const short8*)&lb[offB[0][ks]];
      const short8 b1 = *(const short8*)&lb[offB[1][ks]];
      acc[0][0] = MFMA32(a0, b0, acc[0][0], 0, 0, 0);
      acc[0][1] = MFMA32(a0, b1, acc[0][1], 0, 0, 0);
      acc[1][0] = MFMA32(a1, b0, acc[1][0], 0, 0, 0);
      acc[1][1] = MFMA32(a1, b1, acc[1][1], 0, 0, 0);
    }
  }
#undef PV_STG

  // epilogue: 1/l per row from lpart chunks 0..qt
  __syncthreads();
  if (tid < 128) {
    const float* lp = lpart + (long)zb * 16 * 2048 + m0 + tid;
    float s = 0.f;
    for (int c = 0; c <= qt; ++c) s += lp[(long)c * 2048];
    l_s[tid] = 1.f / s;
  }
  __syncthreads();

  const int ec = lane & 31;
  const int rb = hh * 4;
  float* Cf = out + (long)zb * 2048 * 1024;
#pragma unroll
  for (int i = 0; i < 2; ++i) {
    const int rbl = wm * 64 + i * 32 + rb;
#pragma unroll
    for (int j = 0; j < 2; ++j) {
      const int col = n0 + wn * 64 + j * 32 + ec;
#pragma unroll
      for (int r = 0; r < 16; ++r) {
        const int rl = rbl + (r & 3) + 8 * (r >> 2);
        Cf[(long)(m0 + rl) * 1024 + col] = acc[i][j][r] * l_s[rl];
      }
    }
  }
}

// ---------------------------------------------------------------------------
// Fused casts: blocks [0,8192): X fp32->bf16 (1024 elems each);
// blocks [8192,11264): W_{q,k,v}[k][n] fp32 -> Wt[n][k] bf16 (32x32 tiles).
// ---------------------------------------------------------------------------
__global__ __launch_bounds__(256) void cast_fused(
    const float* __restrict__ x, const float* __restrict__ w0,
    const float* __restrict__ w1, const float* __restrict__ w2,
    u16* __restrict__ Xbf, u16* __restrict__ Wt)
{
  const int b = blockIdx.x;
  if (b < 8192) {
    const long i = ((long)b * 256 + threadIdx.x) * 4;
    const float4 v = *(const float4*)(x + i);
    ushort4 o;
    o.x = f2bf(v.x); o.y = f2bf(v.y); o.z = f2bf(v.z); o.w = f2bf(v.w);
    *(ushort4*)(Xbf + i) = o;
  } else {
    const int bb = b - 8192;               // [0,3072)
    const int z = bb >> 10, rem = bb & 1023;
    const float* W = (z == 0) ? w0 : (z == 1) ? w1 : w2;
    u16* o = Wt + (long)z * 1024 * 1024;
    __shared__ float t[32][33];
    const int n0 = (rem & 31) * 32, k0 = (rem >> 5) * 32;
    const int tx = threadIdx.x & 31, ty = threadIdx.x >> 5;
    for (int r = ty; r < 32; r += 8) t[r][tx] = W[(long)(k0 + r) * 1024 + n0 + tx];
    __syncthreads();
    for (int r = ty; r < 32; r += 8) o[(long)(n0 + r) * 1024 + k0 + tx] = f2bf(t[tx][r]);
  }
}

// ---------------------------------------------------------------------------
extern "C" void kernel_launch(void* const* d_in, const int* in_sizes, int n_in,
                              void* d_out, int out_size, void* d_ws, size_t ws_size,
                              hipStream_t stream) {
  const float* X  = (const float*)d_in[0];
  const float* Wq = (const float*)d_in[1];
  const float* Wk = (const float*)d_in[2];
  const float* Wv = (const float*)d_in[3];
  float* out = (float*)d_out;

  // workspace (~103 MiB)
  u16* Xbf   = (u16*)d_ws;                   // 8192*1024            16 MB
  u16* Wt    = Xbf + 8192L * 1024;           // 3*1024*1024           6 MB
  u16* QK    = Wt + 3L * 1024 * 1024;        // 2*8192*1024          32 MB
  u16* VtAll = QK + 2L * 8192 * 1024;        // 1024*8192            16 MB
  u16* P     = VtAll + 1024L * 8192;         // 4*2048*2048          32 MB
  float* lpart = (float*)(P + 4L * 2048 * 2048);  // 4*16*2048 fp32  0.5 MB

  cast_fused<<<8192 + 3072, 256, 0, stream>>>(X, Wq, Wk, Wv, Xbf, Wt);

  // QK-fused projection (256 full blocks) + Vt (256 half blocks backfill)
  g8<0><<<512, 512, 0, stream>>>(Xbf, Wt, QK, VtAll, P, lpart);

  // causal scores only: one clean round
  g8<1><<<144, 512, 0, stream>>>(Xbf, Wt, QK, VtAll, P, lpart);

  // PV: 512 blocks (2/CU), complementary big+small pairing per CU
  pv<<<512, 256, 0, stream>>>(VtAll, P, lpart, out);
}